// Round 1
// baseline (142.146 us; speedup 1.0000x reference)
//
#include <hip/hip_runtime.h>

#define B 2
#define W 4096
#define R 8
#define D 32
#define L 64
#define C (W / L)   // 64 chunks

// ---------------------------------------------------------------------------
// Kernel 1: per-chunk local decayed state
//   S_loc[b,c,r,d] = sum_{j=0..L-1} gamma_r^(L-1-j) * k[b,cL+j,r] * h[b,cL+j,d]
// grid: B*C blocks of 256 threads (one thread per (r,d) pair)
// ---------------------------------------------------------------------------
__global__ __launch_bounds__(256) void k_local(const float* __restrict__ kin,
                                               const float* __restrict__ hin,
                                               const float* __restrict__ gamma_vec,
                                               float* __restrict__ ws_state) {
    __shared__ float sk[L][R];
    __shared__ float sh[L][D];
    const int blk = blockIdx.x;
    const int b = blk / C, c = blk % C;
    const int t = threadIdx.x;
    const float* kp = kin + ((size_t)b * W + (size_t)c * L) * R;   // [L][R]
    const float* hp = hin + ((size_t)b * W + (size_t)c * L) * D;   // [L][D]
    for (int idx = t; idx < L * R; idx += 256) sk[idx / R][idx % R] = kp[idx];
    for (int idx = t; idx < L * D; idx += 256) sh[idx / D][idx % D] = hp[idx];
    __syncthreads();
    const int r = t >> 5;    // 0..7
    const int d = t & 31;    // 0..31
    const float g = gamma_vec[r];
    float S = 0.f;
#pragma unroll
    for (int j = 0; j < L; ++j) {
        S = S * g + sk[j][r] * sh[j][d];
    }
    ws_state[((size_t)(b * C + c) * R + r) * D + d] = S;
}

// ---------------------------------------------------------------------------
// Kernel 2: in-place exclusive scan over chunks.
// After this, ws_state[b,c,r,d] = state BEFORE chunk c (exclusive prefix):
//   P_c = gamma^L * P_{c-1} + S_loc_{c-1},  P_0 = 0
// grid: 2 blocks x 256 = 512 threads = B*R*D, one scalar scan each.
// ---------------------------------------------------------------------------
__global__ __launch_bounds__(256) void k_scan(const float* __restrict__ gamma_vec,
                                              float* __restrict__ ws_state) {
    const int tid = blockIdx.x * 256 + threadIdx.x;  // 0..511
    const int b = tid >> 8;
    const int rd = tid & 255;
    const int r = rd >> 5;
    float gL = gamma_vec[r];
#pragma unroll
    for (int s = 0; s < 6; ++s) gL *= gL;            // gamma^64
    float S = 0.f;
    float* base = ws_state + (size_t)b * C * R * D + rd;
    for (int c = 0; c < C; ++c) {
        const float v = base[(size_t)c * R * D];
        base[(size_t)c * R * D] = S;
        S = S * gL + v;
    }
}

// ---------------------------------------------------------------------------
// Kernel 3: outputs.
//   out[b,i,d] = sum_r q[i,r]*gamma_r^(ii+1)*P[r,d]                (inter)
//              + sum_{j<=ii} (sum_r q[i,r] k[j,r] gamma_r^(ii-j)) * h[j,d]  (intra)
// grid: B*C blocks of 256 threads; each thread produces 8 (i,d) outputs.
// ---------------------------------------------------------------------------
__global__ __launch_bounds__(256) void k_out(const float* __restrict__ qin,
                                             const float* __restrict__ kin,
                                             const float* __restrict__ hin,
                                             const float* __restrict__ gamma_vec,
                                             const float* __restrict__ ws_state,
                                             float* __restrict__ out) {
    __shared__ float sq[L][R];
    __shared__ float sk[L][R];
    __shared__ float sh[L][D];
    __shared__ float sA[L][L];        // decay-attention matrix, 16 KB
    __shared__ float spow[R][L + 1];  // gamma_r^delta, delta in [0,L]
    __shared__ float s0[R][D];        // carried-in state
    const int blk = blockIdx.x;
    const int b = blk / C, c = blk % C;
    const int t = threadIdx.x;
    const size_t row0 = (size_t)b * W + (size_t)c * L;
    const float* qp = qin + row0 * R;
    const float* kp = kin + row0 * R;
    const float* hp = hin + row0 * D;
    for (int idx = t; idx < L * R; idx += 256) {
        sq[idx / R][idx % R] = qp[idx];
        sk[idx / R][idx % R] = kp[idx];
    }
    for (int idx = t; idx < L * D; idx += 256) sh[idx / D][idx % D] = hp[idx];
    s0[t >> 5][t & 31] = ws_state[(size_t)(b * C + c) * R * D + t];
    if (t < R) {
        const float g = gamma_vec[t];
        float p = 1.f;
        for (int dl = 0; dl <= L; ++dl) { spow[t][dl] = p; p *= g; }
    }
    __syncthreads();

    // Build A[i][j] = sum_r q[i,r] k[j,r] gamma_r^(i-j), zero above diagonal.
    for (int e = t; e < L * L; e += 256) {
        const int i = e >> 6, j = e & 63;
        float a = 0.f;
        if (j <= i) {
#pragma unroll
            for (int r = 0; r < R; ++r) a += sq[i][r] * sk[j][r] * spow[r][i - j];
        }
        sA[i][j] = a;
    }
    __syncthreads();

    const int d = t & 31;
    const int ig = t >> 5;   // 0..7 -> handles i = ig*8 .. ig*8+7
    float acc[8];
#pragma unroll
    for (int s = 0; s < 8; ++s) {
        const int i = ig * 8 + s;
        float a = 0.f;
#pragma unroll
        for (int r = 0; r < R; ++r) a += sq[i][r] * spow[r][i + 1] * s0[r][d];
        acc[s] = a;
    }
    for (int j = 0; j < L; ++j) {
        const float hv = sh[j][d];
#pragma unroll
        for (int s = 0; s < 8; ++s) acc[s] += sA[ig * 8 + s][j] * hv;
    }
#pragma unroll
    for (int s = 0; s < 8; ++s) {
        const int i = ig * 8 + s;
        out[(row0 + (size_t)i) * D + d] = acc[s];
    }
}

extern "C" void kernel_launch(void* const* d_in, const int* in_sizes, int n_in,
                              void* d_out, int out_size, void* d_ws, size_t ws_size,
                              hipStream_t stream) {
    const float* q  = (const float*)d_in[0];   // [B,W,R]
    const float* k  = (const float*)d_in[1];   // [B,W,R]
    const float* h  = (const float*)d_in[2];   // [B,W,D]
    const float* gv = (const float*)d_in[3];   // [R]
    // d_in[4] (causal_mask) and d_in[5] (decay_diff) are implied analytically.
    float* out = (float*)d_out;                // [B,W,D] fp32
    float* ws  = (float*)d_ws;                 // needs B*C*R*D*4 = 256 KB

    k_local<<<B * C, 256, 0, stream>>>(k, h, gv, ws);
    k_scan <<<2,     256, 0, stream>>>(gv, ws);
    k_out  <<<B * C, 256, 0, stream>>>(q, k, h, gv, ws, out);
}